// Round 18
// baseline (436.599 us; speedup 1.0000x reference)
//
#include <hip/hip_runtime.h>

typedef unsigned short u16;
typedef __bf16 bf16x8 __attribute__((ext_vector_type(8)));
typedef float f32x4 __attribute__((ext_vector_type(4)));
typedef unsigned short ushort8 __attribute__((ext_vector_type(8)));

__device__ __forceinline__ void gload_lds16(const void* g, void* l) {
  __builtin_amdgcn_global_load_lds(
      (const __attribute__((address_space(1))) void*)g,
      (__attribute__((address_space(3))) void*)l, 16, 0, 0);
}

__device__ __forceinline__ u16 f2bf(float f) {
  unsigned int u = __builtin_bit_cast(unsigned int, f);
  u = (u + 0x7fffu + ((u >> 16) & 1u)) >> 16;
  return (u16)u;
}
__device__ __forceinline__ u16 f2bf_trunc(float f) {
  return (u16)(__builtin_bit_cast(unsigned int, f) >> 16);
}
__device__ __forceinline__ float bf2f(u16 u) {
  unsigned int v = (unsigned int)u << 16;
  return __builtin_bit_cast(float, v);
}

// ---------------- cast f32 -> bf16 (with optional scale) ----------------
__global__ void castk(const float* __restrict__ in, u16* __restrict__ out, int n,
                      float scale) {
  size_t i = ((size_t)blockIdx.x * 256 + threadIdx.x) * 8;
  if (i >= (size_t)n) return;
  const float4* p = (const float4*)(in + i);
  float4 a = p[0], b = p[1];
  ushort8 o;
  o[0] = f2bf(a.x * scale); o[1] = f2bf(a.y * scale);
  o[2] = f2bf(a.z * scale); o[3] = f2bf(a.w * scale);
  o[4] = f2bf(b.x * scale); o[5] = f2bf(b.y * scale);
  o[6] = f2bf(b.z * scale); o[7] = f2bf(b.w * scale);
  *(ushort8*)(out + i) = o;
}

// ---------------- cast all 4 QKVR weights into fused layout (Q scaled 1/8) ----------------
__global__ void castw4(const float* __restrict__ w0, const float* __restrict__ w1,
                       const float* __restrict__ w2, const float* __restrict__ w3,
                       u16* __restrict__ out) {
  size_t idx = ((size_t)blockIdx.x * 256 + threadIdx.x) * 8;   // NB*4*262144 total
  int i = (int)(idx >> 20);
  int j = (int)((idx >> 18) & 3);
  int e = (int)(idx & 262143);
  const float* src = (j == 0) ? w0 : (j == 1) ? w1 : (j == 2) ? w2 : w3;
  float scale = (j == 0) ? 0.125f : 1.0f;
  const float4* p = (const float4*)(src + (size_t)i * 262144 + e);
  float4 a = p[0], b = p[1];
  ushort8 o;
  o[0] = f2bf(a.x * scale); o[1] = f2bf(a.y * scale);
  o[2] = f2bf(a.z * scale); o[3] = f2bf(a.w * scale);
  o[4] = f2bf(b.x * scale); o[5] = f2bf(b.y * scale);
  o[6] = f2bf(b.z * scale); o[7] = f2bf(b.w * scale);
  *(ushort8*)(out + idx) = o;
}

// ---------------- gather QKVR bias into fused layout (Q scaled by 1/8) ----------------
__global__ void biasg(const float* __restrict__ b0, const float* __restrict__ b1,
                      const float* __restrict__ b2, const float* __restrict__ b3,
                      float* __restrict__ out) {
  int idx = blockIdx.x * 256 + threadIdx.x;    // NB*2048 total
  int i = idx >> 11, j = (idx >> 9) & 3, c = idx & 511;
  const float* src = (j == 0) ? b0 : (j == 1) ? b1 : (j == 2) ? b2 : b3;
  float v = src[i * 512 + c];
  out[idx] = (j == 0) ? v * 0.125f : v;
}

// ======== m97-style GEMM: 256 threads / 4 waves, 128x128 tile, BK=64,
// ======== single 32KB LDS buffer -> 4 blocks/CU. Best of 7 measured variants.
template<int RELU, int WVT>
__global__ __launch_bounds__(256, 4)
void gemm97(const u16* __restrict__ A, const u16* __restrict__ W,
            const float* __restrict__ bias, u16* __restrict__ C,
            u16* __restrict__ VT, int M, int N, int K)
{
  __shared__ char lds[32768];
  char* ABase = lds;
  char* BBase = lds + 16384;

  const int tid = threadIdx.x, w = tid >> 6, l = tid & 63;
  const int l15 = l & 15, lh = l >> 4;
  const int nbn = N >> 7;
  const int p = blockIdx.x;
  const int bm = (p & 7) * 16 + (p >> 3) / nbn;   // XCD-chunked swizzle
  const int bn = (p >> 3) % nbn;
  const int wm = w >> 1, wn = w & 1;
  const int NT = K >> 6;

  const int srow = l >> 3;
  const int scol = ((l & 7) ^ srow) << 3;
  const u16* aG = A + (size_t)(bm * 128 + srow) * K + scol;
  const u16* bG = W + (size_t)(bn * 128 + srow) * K + scol;

  auto stage = [&](int t) {
#pragma unroll
    for (int i = 0; i < 4; ++i) {
      int c = w * 4 + i;
      gload_lds16(aG + (size_t)(c * 8) * K + t * 64, ABase + c * 1024);
      gload_lds16(bG + (size_t)(c * 8) * K + t * 64, BBase + c * 1024);
    }
  };

  f32x4 acc[4][4] = {};

  for (int t = 0; t < NT; ++t) {
    __syncthreads();
    stage(t);
    __syncthreads();
    bf16x8 a[4], b[4];
#pragma unroll
    for (int kk = 0; kk < 2; ++kk) {
#pragma unroll
      for (int mf = 0; mf < 4; ++mf) {
        int row = wm * 64 + mf * 16 + l15;
        a[mf] = *(const bf16x8*)(ABase + row * 128 +
                 ((kk * 64 + lh * 16) ^ ((row & 7) << 4)));
      }
#pragma unroll
      for (int nf = 0; nf < 4; ++nf) {
        int row = wn * 64 + nf * 16 + l15;
        b[nf] = *(const bf16x8*)(BBase + row * 128 +
                 ((kk * 64 + lh * 16) ^ ((row & 7) << 4)));
      }
      __builtin_amdgcn_s_setprio(1);
#pragma unroll
      for (int mf = 0; mf < 4; ++mf)
#pragma unroll
        for (int nf = 0; nf < 4; ++nf)
          acc[mf][nf] = __builtin_amdgcn_mfma_f32_16x16x32_bf16(a[mf], b[nf], acc[mf][nf], 0, 0, 0);
      __builtin_amdgcn_s_setprio(0);
    }
  }

  // ---------- LDS-staged epilogue ----------
  __syncthreads();
  char* Ct = (char*)lds;
  const int rowL = wm * 64 + (lh << 2);
  const int colL = wn * 64 + l15;
  // V columns are [1024,1536): with BN=128 tiles that is bn 8..11.
  const bool dovt = WVT && (bn >= 8) && (bn < 12);
  float bv[4];
#pragma unroll
  for (int nf = 0; nf < 4; ++nf) bv[nf] = bias[bn * 128 + colL + nf * 16];

  if (!dovt) {
#pragma unroll
    for (int mf = 0; mf < 4; ++mf)
#pragma unroll
      for (int nf = 0; nf < 4; ++nf)
#pragma unroll
        for (int r = 0; r < 4; ++r) {
          float v = acc[mf][nf][r] + bv[nf];
          if (RELU) v = fmaxf(v, 0.f);
          int m = rowL + mf * 16 + r, n = colL + nf * 16;
          *(u16*)(Ct + m * 256 + ((n * 2) ^ ((m & 7) << 4))) = f2bf(v);
        }
    __syncthreads();
#pragma unroll
    for (int pass = 0; pass < 8; ++pass) {
      int row = pass * 16 + (tid >> 4);
      int c16 = tid & 15;
      bf16x8 vv = *(const bf16x8*)(Ct + row * 256 + ((c16 * 16) ^ ((row & 7) << 4)));
      *(bf16x8*)(&C[(size_t)(bm * 128 + row) * N + bn * 128 + c16 * 8]) = vv;
    }
  } else {
    // transposed tile [128 d][128 m] -> VT coalesced
#pragma unroll
    for (int mf = 0; mf < 4; ++mf)
#pragma unroll
      for (int nf = 0; nf < 4; ++nf)
#pragma unroll
        for (int r = 0; r < 4; ++r) {
          float v = acc[mf][nf][r] + bv[nf];
          if (RELU) v = fmaxf(v, 0.f);
          int m = rowL + mf * 16 + r, d = colL + nf * 16;
          *(u16*)(Ct + d * 256 + ((m * 2) ^ ((d & 7) << 4))) = f2bf(v);
        }
    __syncthreads();
    const int batch = bm >> 2;
#pragma unroll
    for (int pass = 0; pass < 8; ++pass) {
      int dL = pass * 16 + (tid >> 4);
      int m16 = tid & 15;
      bf16x8 vv = *(const bf16x8*)(Ct + dL * 256 + ((m16 * 16) ^ ((dL & 7) << 4)));
      int head = (bn - 8) * 2 + (dL >> 6);
      int vtr = (batch * 8 + head) * 64 + (dL & 63);
      *(bf16x8*)(&VT[(size_t)vtr * 512 + (bm & 3) * 128 + m16 * 8]) = vv;
    }
  }
}

// ---------------- fused attention: F = softmax(QK^T/8) V + R  (per b,h) ----------------
// 2 q-tiles (256 rows) per block: each staged K/V tile feeds both tiles;
// grid 512 -> all blocks co-resident (no ragged tail). Q of both tiles hoisted
// to registers; one 16KB QPs region reused for P of each tile sequentially
// (P rows wave-private; same-wave DS ops are in-order). LDS 48KB -> 3 blk/CU.
__global__ __launch_bounds__(256, 3)
void attn_kernel(const u16* __restrict__ qkvr, const u16* __restrict__ VT,
                 u16* __restrict__ F)
{
  const int D4 = 2048;
  __shared__ u16 QPs[128 * 64];   // Q staging (x2), then P scratch (16KB)
  __shared__ u16 Ks[2][64 * 64];
  __shared__ u16 Vs[2][64 * 64];

  const int tid = threadIdx.x, w = tid >> 6, l = tid & 63;
  const int bh = blockIdx.x & 255, qp = blockIdx.x >> 8;   // qp = 0,1
  const int b = bh >> 3, h = bh & 7;
  const int lr = l >> 3, lc = ((l & 7) ^ lr) << 3;
  const int l15 = l & 15, lh = l >> 4;

  const u16* qG = qkvr + (size_t)(b * 512 + qp * 256) * D4 + h * 64 + lc;
  const u16* kG = qkvr + (size_t)(b * 512) * D4 + 512 + h * 64 + lc;
  const u16* vG = VT + (size_t)(bh * 64) * 512 + lc;

  auto stageQ = [&](int t) {             // t = 0,1 (128 rows each)
#pragma unroll
    for (int i = 0; i < 4; ++i) {
      int c = w * 4 + i;
      gload_lds16(qG + (size_t)(t * 128 + c * 8 + lr) * D4, &QPs[c * 512]);
    }
  };
  auto stageKV = [&](int kt) {
    const int bsel = kt & 1;
#pragma unroll
    for (int i = 0; i < 2; ++i) {
      int c = w * 2 + i;
      gload_lds16(kG + (size_t)(kt * 64 + c * 8 + lr) * D4, &Ks[bsel][c * 512]);
      gload_lds16(vG + (size_t)(c * 8 + lr) * 512 + kt * 64, &Vs[bsel][c * 512]);
    }
  };

  bf16x8 qa[2][2][2];                    // [qt][kk][qq]

  stageQ(0);
  stageKV(0);
  __syncthreads();                       // Q0 + KV0 landed
#pragma unroll
  for (int kk = 0; kk < 2; ++kk)
#pragma unroll
    for (int qq = 0; qq < 2; ++qq) {
      int qrow = w * 32 + qq * 16 + l15;
      qa[0][kk][qq] = *(const bf16x8*)((const char*)QPs + qrow * 128 +
                       ((kk * 64 + (lh << 4)) ^ ((qrow & 7) << 4)));
    }
  __syncthreads();                       // Q0 hoists complete (lgkm drained)
  stageQ(1);
  __syncthreads();                       // Q1 landed
#pragma unroll
  for (int kk = 0; kk < 2; ++kk)
#pragma unroll
    for (int qq = 0; qq < 2; ++qq) {
      int qrow = w * 32 + qq * 16 + l15;
      qa[1][kk][qq] = *(const bf16x8*)((const char*)QPs + qrow * 128 +
                       ((kk * 64 + (lh << 4)) ^ ((qrow & 7) << 4)));
    }

  f32x4 o_acc[2][2][4] = {};             // [qt][qq][ni]
  float psum[2][2][4] = {};

  for (int kt = 0; kt < 8; ++kt) {
    if (kt) __syncthreads();             // KV(kt) landed; buffer kt+1 free
    if (kt < 7) stageKV(kt + 1);
    const char* Kb = (const char*)Ks[kt & 1];
    const char* Vb = (const char*)Vs[kt & 1];

#pragma unroll
    for (int qt = 0; qt < 2; ++qt) {
      f32x4 sacc[2][4] = {};
#pragma unroll
      for (int kk = 0; kk < 2; ++kk) {
#pragma unroll
        for (int ni = 0; ni < 4; ++ni) {
          int krow = ni * 16 + l15;
          bf16x8 kb = *(const bf16x8*)(Kb + krow * 128 +
                      ((kk * 64 + (lh << 4)) ^ ((krow & 7) << 4)));
#pragma unroll
          for (int qq = 0; qq < 2; ++qq)
            sacc[qq][ni] = __builtin_amdgcn_mfma_f32_16x16x32_bf16(qa[qt][kk][qq], kb, sacc[qq][ni], 0, 0, 0);
        }
      }

#pragma unroll
      for (int qq = 0; qq < 2; ++qq)
#pragma unroll
        for (int r = 0; r < 4; ++r) {
          float p0 = __expf(sacc[qq][0][r]);
          float p1 = __expf(sacc[qq][1][r]);
          float p2 = __expf(sacc[qq][2][r]);
          float p3 = __expf(sacc[qq][3][r]);
          psum[qt][qq][r] += (p0 + p1) + (p2 + p3);
          int q = w * 32 + qq * 16 + (lh << 2) + r;
          int sw = (q & 7) << 4;
          int col = l15 * 2;
          char* pb = (char*)QPs + q * 128;
          *(u16*)(pb + ((0  + col) ^ sw)) = f2bf_trunc(p0);
          *(u16*)(pb + ((32 + col) ^ sw)) = f2bf_trunc(p1);
          *(u16*)(pb + ((64 + col) ^ sw)) = f2bf_trunc(p2);
          *(u16*)(pb + ((96 + col) ^ sw)) = f2bf_trunc(p3);
        }

#pragma unroll
      for (int kk = 0; kk < 2; ++kk) {
        bf16x8 pa[2];
#pragma unroll
        for (int qq = 0; qq < 2; ++qq) {
          int qrow = w * 32 + qq * 16 + l15;
          pa[qq] = *(const bf16x8*)((const char*)QPs + qrow * 128 +
                    ((kk * 64 + (lh << 4)) ^ ((qrow & 7) << 4)));
        }
#pragma unroll
        for (int ni = 0; ni < 4; ++ni) {
          int d = ni * 16 + l15;
          bf16x8 vb = *(const bf16x8*)(Vb + d * 128 +
                      ((kk * 64 + (lh << 4)) ^ ((d & 7) << 4)));
#pragma unroll
          for (int qq = 0; qq < 2; ++qq)
            o_acc[qt][qq][ni] = __builtin_amdgcn_mfma_f32_16x16x32_bf16(pa[qq], vb, o_acc[qt][qq][ni], 0, 0, 0);
        }
      }
    }
  }

  float lsum[2][2][4];
#pragma unroll
  for (int qt = 0; qt < 2; ++qt)
#pragma unroll
    for (int qq = 0; qq < 2; ++qq)
#pragma unroll
      for (int r = 0; r < 4; ++r) {
        float t = psum[qt][qq][r];
#pragma unroll
        for (int m = 1; m < 16; m <<= 1) t += __shfl_xor(t, m);
        lsum[qt][qq][r] = 1.f / t;
      }

  // ---------- LDS-staged epilogue per q-tile (QPs reused sequentially) ----------
#pragma unroll
  for (int qt = 0; qt < 2; ++qt) {
    if (qt) __syncthreads();             // previous tile's F-pass reads done
#pragma unroll
    for (int qq = 0; qq < 2; ++qq)
#pragma unroll
      for (int ni = 0; ni < 4; ++ni) {
        int d = ni * 16 + l15;
#pragma unroll
        for (int r = 0; r < 4; ++r) {
          float v = o_acc[qt][qq][ni][r] * lsum[qt][qq][r];
          int q = w * 32 + qq * 16 + (lh << 2) + r;
          *(u16*)((char*)QPs + q * 128 + ((d * 2) ^ ((q & 7) << 4))) = f2bf(v);
        }
      }
    __syncthreads();                     // O writes visible block-wide
    const u16* Rbase = qkvr + (size_t)(b * 512 + qp * 256 + qt * 128) * D4 + 1536 + h * 64;
    u16* Fbase = F + (size_t)(b * 512 + qp * 256 + qt * 128) * 512 + h * 64;
#pragma unroll
    for (int pass = 0; pass < 4; ++pass) {
      int row = pass * 32 + (tid >> 3), c8 = tid & 7;
      ushort8 lv = *(const ushort8*)((char*)QPs + row * 128 + ((c8 * 16) ^ ((row & 7) << 4)));
      ushort8 rv = *(const ushort8*)(Rbase + (size_t)row * D4 + c8 * 8);
      ushort8 o;
#pragma unroll
      for (int j = 0; j < 8; ++j) o[j] = f2bf(bf2f(lv[j]) + bf2f(rv[j]));
      *(ushort8*)(Fbase + (size_t)row * 512 + c8 * 8) = o;
    }
  }
}

// ---------------- LayerNorm over 512 bf16 ----------------
template<int HAS_RES, int OUT_F32>
__global__ __launch_bounds__(256)
void ln_bf(const u16* __restrict__ in, const u16* __restrict__ res,
           const float* __restrict__ gamma, const float* __restrict__ beta,
           u16* __restrict__ outb, float* __restrict__ outf)
{
  const int l = threadIdx.x & 63;
  const size_t row = (size_t)blockIdx.x * 4 + (threadIdx.x >> 6);
  ushort8 iv = *(const ushort8*)(in + row * 512 + l * 8);
  float x[8];
#pragma unroll
  for (int j = 0; j < 8; ++j) x[j] = bf2f(iv[j]);
  if (HAS_RES) {
    ushort8 rv = *(const ushort8*)(res + row * 512 + l * 8);
#pragma unroll
    for (int j = 0; j < 8; ++j) x[j] += bf2f(rv[j]);
  }
  float s = 0.f, ss = 0.f;
#pragma unroll
  for (int j = 0; j < 8; ++j) { s += x[j]; ss += x[j] * x[j]; }
#pragma unroll
  for (int m = 1; m < 64; m <<= 1) { s += __shfl_xor(s, m); ss += __shfl_xor(ss, m); }
  float mean = s * (1.f / 512.f);
  float var = fmaxf((ss - 512.f * mean * mean) * (1.f / 511.f), 0.f);
  float inv = 1.f / (sqrtf(var) + 1e-8f);
  const float4* g4 = (const float4*)gamma;
  const float4* b4 = (const float4*)beta;
  float4 g0 = g4[l * 2], g1 = g4[l * 2 + 1];
  float4 b0 = b4[l * 2], b1 = b4[l * 2 + 1];
  float gg[8] = {g0.x, g0.y, g0.z, g0.w, g1.x, g1.y, g1.z, g1.w};
  float bb[8] = {b0.x, b0.y, b0.z, b0.w, b1.x, b1.y, b1.z, b1.w};
  float y[8];
#pragma unroll
  for (int j = 0; j < 8; ++j) y[j] = gg[j] * (x[j] - mean) * inv + bb[j];
  if (outb) {
    ushort8 o;
#pragma unroll
    for (int j = 0; j < 8; ++j) o[j] = f2bf(y[j]);
    *(ushort8*)(outb + row * 512 + l * 8) = o;
  }
  if (OUT_F32) {
    float4* o4 = (float4*)(outf + row * 512);
    o4[l * 2]     = make_float4(y[0], y[1], y[2], y[3]);
    o4[l * 2 + 1] = make_float4(y[4], y[5], y[6], y[7]);
  }
}

extern "C" void kernel_launch(void* const* d_in, const int* in_sizes, int n_in,
                              void* d_out, int out_size, void* d_ws, size_t ws_size,
                              hipStream_t stream)
{
  const int B = 32, S = 512, D = 512, NB = 2, DF = 2048;
  const int M = B * S;

  const float* x   = (const float*)d_in[0];
  const float* ga  = (const float*)d_in[9];
  const float* ba  = (const float*)d_in[10];
  const float* wc1 = (const float*)d_in[11];
  const float* bc1 = (const float*)d_in[12];
  const float* wc2 = (const float*)d_in[13];
  const float* bc2 = (const float*)d_in[14];
  const float* gf  = (const float*)d_in[15];
  const float* bfp = (const float*)d_in[16];

  char* ws = (char*)d_ws;
  u16*   curb = (u16*)(ws + 0);                    // 16 MB
  u16*   qkvr = (u16*)(ws + 16777216);             // 64 MB (aliases Ih)
  u16*   F    = (u16*)(ws + 83886080);             // 16 MB (aliases Y)
  u16*   Hg   = (u16*)(ws + 100663296);            // 16 MB
  u16*   VT   = (u16*)(ws + 117440512);            // 16 MB
  u16*   w4b  = (u16*)(ws + 134217728);            // 4 MB
  u16*   wc1b = (u16*)(ws + 138412032);            // 4 MB
  u16*   wc2b = (u16*)(ws + 142606336);            // 4 MB
  float* b4   = (float*)(ws + 146800640);          // 16 KB
  u16*   Ih   = qkvr;
  u16*   Y    = F;

  castk<<<M * D / 2048, 256, 0, stream>>>(x, curb, M * D, 1.0f);
  castw4<<<1024, 256, 0, stream>>>((const float*)d_in[1], (const float*)d_in[3],
                                   (const float*)d_in[5], (const float*)d_in[7], w4b);
  biasg<<<16, 256, 0, stream>>>((const float*)d_in[2], (const float*)d_in[4],
                                (const float*)d_in[6], (const float*)d_in[8], b4);
  castk<<<NB * DF * D / 2048, 256, 0, stream>>>(wc1, wc1b, NB * DF * D, 1.0f);
  castk<<<NB * DF * D / 2048, 256, 0, stream>>>(wc2, wc2b, NB * DF * D, 1.0f);

  for (int i = 0; i < NB; ++i) {
    const size_t wfo = (size_t)i * DF * D;
    gemm97<1, 1><<<128 * 16, 256, 0, stream>>>(curb, w4b + (size_t)i * 1048576,
                                               b4 + i * 2048, qkvr, VT, M, 2048, 512);
    attn_kernel<<<2 * 256, 256, 0, stream>>>(qkvr, VT, F);
    ln_bf<0, 0><<<M / 4, 256, 0, stream>>>(F, nullptr, ga + i * D, ba + i * D, Hg, nullptr);
    gemm97<1, 0><<<128 * 16, 256, 0, stream>>>(Hg, wc1b + wfo, bc1 + i * DF,
                                               Ih, nullptr, M, 2048, 512);
    gemm97<0, 0><<<128 * 4, 256, 0, stream>>>(Ih, wc2b + wfo, bc2 + i * D,
                                              Y, nullptr, M, 512, 2048);
    if (i == NB - 1)
      ln_bf<1, 1><<<M / 4, 256, 0, stream>>>(Y, Hg, gf + i * D, bfp + i * D,
                                             nullptr, (float*)d_out);
    else
      ln_bf<1, 0><<<M / 4, 256, 0, stream>>>(Y, Hg, gf + i * D, bfp + i * D,
                                             curb, nullptr);
  }
}

// Round 19
// 357.195 us; speedup vs baseline: 1.2223x; 1.2223x over previous
//
#include <hip/hip_runtime.h>

typedef unsigned short u16;
typedef __bf16 bf16x8 __attribute__((ext_vector_type(8)));
typedef float f32x4 __attribute__((ext_vector_type(4)));
typedef unsigned short ushort8 __attribute__((ext_vector_type(8)));

__device__ __forceinline__ void gload_lds16(const void* g, void* l) {
  __builtin_amdgcn_global_load_lds(
      (const __attribute__((address_space(1))) void*)g,
      (__attribute__((address_space(3))) void*)l, 16, 0, 0);
}

__device__ __forceinline__ u16 f2bf(float f) {
  unsigned int u = __builtin_bit_cast(unsigned int, f);
  u = (u + 0x7fffu + ((u >> 16) & 1u)) >> 16;
  return (u16)u;
}
__device__ __forceinline__ u16 f2bf_trunc(float f) {
  return (u16)(__builtin_bit_cast(unsigned int, f) >> 16);
}
__device__ __forceinline__ float bf2f(u16 u) {
  unsigned int v = (unsigned int)u << 16;
  return __builtin_bit_cast(float, v);
}

// ---------------- cast f32 -> bf16 (with optional scale) ----------------
__global__ void castk(const float* __restrict__ in, u16* __restrict__ out, int n,
                      float scale) {
  size_t i = ((size_t)blockIdx.x * 256 + threadIdx.x) * 8;
  if (i >= (size_t)n) return;
  const float4* p = (const float4*)(in + i);
  float4 a = p[0], b = p[1];
  ushort8 o;
  o[0] = f2bf(a.x * scale); o[1] = f2bf(a.y * scale);
  o[2] = f2bf(a.z * scale); o[3] = f2bf(a.w * scale);
  o[4] = f2bf(b.x * scale); o[5] = f2bf(b.y * scale);
  o[6] = f2bf(b.z * scale); o[7] = f2bf(b.w * scale);
  *(ushort8*)(out + i) = o;
}

// ---------------- cast all 4 QKVR weights into fused layout (Q scaled 1/8) ----------------
__global__ void castw4(const float* __restrict__ w0, const float* __restrict__ w1,
                       const float* __restrict__ w2, const float* __restrict__ w3,
                       u16* __restrict__ out) {
  size_t idx = ((size_t)blockIdx.x * 256 + threadIdx.x) * 8;   // NB*4*262144 total
  int i = (int)(idx >> 20);
  int j = (int)((idx >> 18) & 3);
  int e = (int)(idx & 262143);
  const float* src = (j == 0) ? w0 : (j == 1) ? w1 : (j == 2) ? w2 : w3;
  float scale = (j == 0) ? 0.125f : 1.0f;
  const float4* p = (const float4*)(src + (size_t)i * 262144 + e);
  float4 a = p[0], b = p[1];
  ushort8 o;
  o[0] = f2bf(a.x * scale); o[1] = f2bf(a.y * scale);
  o[2] = f2bf(a.z * scale); o[3] = f2bf(a.w * scale);
  o[4] = f2bf(b.x * scale); o[5] = f2bf(b.y * scale);
  o[6] = f2bf(b.z * scale); o[7] = f2bf(b.w * scale);
  *(ushort8*)(out + idx) = o;
}

// ---------------- gather QKVR bias into fused layout (Q scaled by 1/8) ----------------
__global__ void biasg(const float* __restrict__ b0, const float* __restrict__ b1,
                      const float* __restrict__ b2, const float* __restrict__ b3,
                      float* __restrict__ out) {
  int idx = blockIdx.x * 256 + threadIdx.x;    // NB*2048 total
  int i = idx >> 11, j = (idx >> 9) & 3, c = idx & 511;
  const float* src = (j == 0) ? b0 : (j == 1) ? b1 : (j == 2) ? b2 : b3;
  float v = src[i * 512 + c];
  out[idx] = (j == 0) ? v * 0.125f : v;
}

// ======== m97-style GEMM: 256 threads / 4 waves, 128x128 tile, BK=64,
// ======== single 32KB LDS buffer -> 4 blocks/CU. Best of 7 measured variants.
template<int RELU, int WVT>
__global__ __launch_bounds__(256, 4)
void gemm97(const u16* __restrict__ A, const u16* __restrict__ W,
            const float* __restrict__ bias, u16* __restrict__ C,
            u16* __restrict__ VT, int M, int N, int K)
{
  __shared__ char lds[32768];
  char* ABase = lds;
  char* BBase = lds + 16384;

  const int tid = threadIdx.x, w = tid >> 6, l = tid & 63;
  const int l15 = l & 15, lh = l >> 4;
  const int nbn = N >> 7;
  const int p = blockIdx.x;
  const int bm = (p & 7) * 16 + (p >> 3) / nbn;   // XCD-chunked swizzle
  const int bn = (p >> 3) % nbn;
  const int wm = w >> 1, wn = w & 1;
  const int NT = K >> 6;

  const int srow = l >> 3;
  const int scol = ((l & 7) ^ srow) << 3;
  const u16* aG = A + (size_t)(bm * 128 + srow) * K + scol;
  const u16* bG = W + (size_t)(bn * 128 + srow) * K + scol;

  auto stage = [&](int t) {
#pragma unroll
    for (int i = 0; i < 4; ++i) {
      int c = w * 4 + i;
      gload_lds16(aG + (size_t)(c * 8) * K + t * 64, ABase + c * 1024);
      gload_lds16(bG + (size_t)(c * 8) * K + t * 64, BBase + c * 1024);
    }
  };

  f32x4 acc[4][4] = {};

  for (int t = 0; t < NT; ++t) {
    __syncthreads();
    stage(t);
    __syncthreads();
    bf16x8 a[4], b[4];
#pragma unroll
    for (int kk = 0; kk < 2; ++kk) {
#pragma unroll
      for (int mf = 0; mf < 4; ++mf) {
        int row = wm * 64 + mf * 16 + l15;
        a[mf] = *(const bf16x8*)(ABase + row * 128 +
                 ((kk * 64 + lh * 16) ^ ((row & 7) << 4)));
      }
#pragma unroll
      for (int nf = 0; nf < 4; ++nf) {
        int row = wn * 64 + nf * 16 + l15;
        b[nf] = *(const bf16x8*)(BBase + row * 128 +
                 ((kk * 64 + lh * 16) ^ ((row & 7) << 4)));
      }
      __builtin_amdgcn_s_setprio(1);
#pragma unroll
      for (int mf = 0; mf < 4; ++mf)
#pragma unroll
        for (int nf = 0; nf < 4; ++nf)
          acc[mf][nf] = __builtin_amdgcn_mfma_f32_16x16x32_bf16(a[mf], b[nf], acc[mf][nf], 0, 0, 0);
      __builtin_amdgcn_s_setprio(0);
    }
  }

  // ---------- LDS-staged epilogue ----------
  __syncthreads();
  char* Ct = (char*)lds;
  const int rowL = wm * 64 + (lh << 2);
  const int colL = wn * 64 + l15;
  // V columns are [1024,1536): with BN=128 tiles that is bn 8..11.
  const bool dovt = WVT && (bn >= 8) && (bn < 12);
  float bv[4];
#pragma unroll
  for (int nf = 0; nf < 4; ++nf) bv[nf] = bias[bn * 128 + colL + nf * 16];

  if (!dovt) {
#pragma unroll
    for (int mf = 0; mf < 4; ++mf)
#pragma unroll
      for (int nf = 0; nf < 4; ++nf)
#pragma unroll
        for (int r = 0; r < 4; ++r) {
          float v = acc[mf][nf][r] + bv[nf];
          if (RELU) v = fmaxf(v, 0.f);
          int m = rowL + mf * 16 + r, n = colL + nf * 16;
          *(u16*)(Ct + m * 256 + ((n * 2) ^ ((m & 7) << 4))) = f2bf(v);
        }
    __syncthreads();
#pragma unroll
    for (int pass = 0; pass < 8; ++pass) {
      int row = pass * 16 + (tid >> 4);
      int c16 = tid & 15;
      bf16x8 vv = *(const bf16x8*)(Ct + row * 256 + ((c16 * 16) ^ ((row & 7) << 4)));
      *(bf16x8*)(&C[(size_t)(bm * 128 + row) * N + bn * 128 + c16 * 8]) = vv;
    }
  } else {
    // transposed tile [128 d][128 m] -> VT coalesced
#pragma unroll
    for (int mf = 0; mf < 4; ++mf)
#pragma unroll
      for (int nf = 0; nf < 4; ++nf)
#pragma unroll
        for (int r = 0; r < 4; ++r) {
          float v = acc[mf][nf][r] + bv[nf];
          if (RELU) v = fmaxf(v, 0.f);
          int m = rowL + mf * 16 + r, d = colL + nf * 16;
          *(u16*)(Ct + d * 256 + ((m * 2) ^ ((d & 7) << 4))) = f2bf(v);
        }
    __syncthreads();
    const int batch = bm >> 2;
#pragma unroll
    for (int pass = 0; pass < 8; ++pass) {
      int dL = pass * 16 + (tid >> 4);
      int m16 = tid & 15;
      bf16x8 vv = *(const bf16x8*)(Ct + dL * 256 + ((m16 * 16) ^ ((dL & 7) << 4)));
      int head = (bn - 8) * 2 + (dL >> 6);
      int vtr = (batch * 8 + head) * 64 + (dL & 63);
      *(bf16x8*)(&VT[(size_t)vtr * 512 + (bm & 3) * 128 + m16 * 8]) = vv;
    }
  }
}

// ---------------- fused attention: F = softmax(QK^T/8) V + R  (per b,h) ----------------
// Q fragments hoisted to registers once; Qs LDS region reused as Ps
// (wave-private rows; same-wave DS ordering makes aliasing safe).
// K/V double-buffered with post-barrier prefetch. LDS 48KB -> 3 blocks/CU.
__global__ __launch_bounds__(256, 3)
void attn_kernel(const u16* __restrict__ qkvr, const u16* __restrict__ VT,
                 u16* __restrict__ F)
{
  const int D4 = 2048;
  __shared__ u16 QPs[128 * 64];   // Q staged here, then reused for P
  __shared__ u16 Ks[2][64 * 64];
  __shared__ u16 Vs[2][64 * 64];

  const int tid = threadIdx.x, w = tid >> 6, l = tid & 63;
  const int bh = blockIdx.x & 255, qt = blockIdx.x >> 8;
  const int b = bh >> 3, h = bh & 7;
  const int lr = l >> 3, lc = ((l & 7) ^ lr) << 3;
  const int l15 = l & 15, lh = l >> 4;

  const u16* qG = qkvr + (size_t)(b * 512 + qt * 128) * D4 + h * 64 + lc;
#pragma unroll
  for (int i = 0; i < 4; ++i) {
    int c = w * 4 + i;
    gload_lds16(qG + (size_t)(c * 8 + lr) * D4, &QPs[c * 512]);
  }

  const u16* kG = qkvr + (size_t)(b * 512) * D4 + 512 + h * 64 + lc;
  const u16* vG = VT + (size_t)(bh * 64) * 512 + lc;

  auto stageKV = [&](int kt) {
    const int bsel = kt & 1;
#pragma unroll
    for (int i = 0; i < 2; ++i) {
      int c = w * 2 + i;
      gload_lds16(kG + (size_t)(kt * 64 + c * 8 + lr) * D4, &Ks[bsel][c * 512]);
      gload_lds16(vG + (size_t)(c * 8 + lr) * 512 + kt * 64, &Vs[bsel][c * 512]);
    }
  };
  stageKV(0);
  __syncthreads();                        // Q + KV(0) landed

  // hoist Q fragments to registers (frees QPs for P)
  bf16x8 qa[2][2];                        // [kk][qq]
#pragma unroll
  for (int kk = 0; kk < 2; ++kk)
#pragma unroll
    for (int qq = 0; qq < 2; ++qq) {
      int qrow = w * 32 + qq * 16 + l15;
      qa[kk][qq] = *(const bf16x8*)((const char*)QPs + qrow * 128 +
                    ((kk * 64 + (lh << 4)) ^ ((qrow & 7) << 4)));
    }

  f32x4 o_acc[2][4] = {};
  float psum[2][4] = {};

  for (int kt = 0; kt < 8; ++kt) {
    if (kt) __syncthreads();              // KV(kt) landed; buffer kt+1 free
    if (kt < 7) stageKV(kt + 1);
    const char* Kb = (const char*)Ks[kt & 1];
    const char* Vb = (const char*)Vs[kt & 1];

    f32x4 sacc[2][4] = {};
#pragma unroll
    for (int kk = 0; kk < 2; ++kk) {
#pragma unroll
      for (int ni = 0; ni < 4; ++ni) {
        int krow = ni * 16 + l15;
        bf16x8 kb = *(const bf16x8*)(Kb + krow * 128 +
                    ((kk * 64 + (lh << 4)) ^ ((krow & 7) << 4)));
#pragma unroll
        for (int qq = 0; qq < 2; ++qq)
          sacc[qq][ni] = __builtin_amdgcn_mfma_f32_16x16x32_bf16(qa[kk][qq], kb, sacc[qq][ni], 0, 0, 0);
      }
    }

#pragma unroll
    for (int qq = 0; qq < 2; ++qq)
#pragma unroll
      for (int r = 0; r < 4; ++r) {
        float p0 = __expf(sacc[qq][0][r]);
        float p1 = __expf(sacc[qq][1][r]);
        float p2 = __expf(sacc[qq][2][r]);
        float p3 = __expf(sacc[qq][3][r]);
        psum[qq][r] += (p0 + p1) + (p2 + p3);
        int q = w * 32 + qq * 16 + (lh << 2) + r;
        int sw = (q & 7) << 4;
        int col = l15 * 2;
        char* pb = (char*)QPs + q * 128;
        *(u16*)(pb + ((0  + col) ^ sw)) = f2bf_trunc(p0);
        *(u16*)(pb + ((32 + col) ^ sw)) = f2bf_trunc(p1);
        *(u16*)(pb + ((64 + col) ^ sw)) = f2bf_trunc(p2);
        *(u16*)(pb + ((96 + col) ^ sw)) = f2bf_trunc(p3);
      }

#pragma unroll
    for (int kk = 0; kk < 2; ++kk) {
      bf16x8 pa[2];
#pragma unroll
      for (int qq = 0; qq < 2; ++qq) {
        int qrow = w * 32 + qq * 16 + l15;
        pa[qq] = *(const bf16x8*)((const char*)QPs + qrow * 128 +
                  ((kk * 64 + (lh << 4)) ^ ((qrow & 7) << 4)));
      }
#pragma unroll
      for (int ni = 0; ni < 4; ++ni) {
        int d = ni * 16 + l15;
        bf16x8 vb = *(const bf16x8*)(Vb + d * 128 +
                    ((kk * 64 + (lh << 4)) ^ ((d & 7) << 4)));
#pragma unroll
        for (int qq = 0; qq < 2; ++qq)
          o_acc[qq][ni] = __builtin_amdgcn_mfma_f32_16x16x32_bf16(pa[qq], vb, o_acc[qq][ni], 0, 0, 0);
      }
    }
  }

  float lsum[2][4];
#pragma unroll
  for (int qq = 0; qq < 2; ++qq)
#pragma unroll
    for (int r = 0; r < 4; ++r) {
      float t = psum[qq][r];
#pragma unroll
      for (int m = 1; m < 16; m <<= 1) t += __shfl_xor(t, m);
      lsum[qq][r] = 1.f / t;
    }

  // ---------- LDS-staged epilogue (reuse QPs; rows are wave-private) ----------
#pragma unroll
  for (int qq = 0; qq < 2; ++qq)
#pragma unroll
    for (int ni = 0; ni < 4; ++ni) {
      int d = ni * 16 + l15;
#pragma unroll
      for (int r = 0; r < 4; ++r) {
        float v = o_acc[qq][ni][r] * lsum[qq][r];
        int q = w * 32 + qq * 16 + (lh << 2) + r;
        *(u16*)((char*)QPs + q * 128 + ((d * 2) ^ ((q & 7) << 4))) = f2bf(v);
      }
    }
  __syncthreads();
  const u16* Rbase = qkvr + (size_t)(b * 512 + qt * 128) * D4 + 1536 + h * 64;
  u16* Fbase = F + (size_t)(b * 512 + qt * 128) * 512 + h * 64;
#pragma unroll
  for (int pass = 0; pass < 4; ++pass) {
    int row = pass * 32 + (tid >> 3), c8 = tid & 7;
    ushort8 lv = *(const ushort8*)((char*)QPs + row * 128 + ((c8 * 16) ^ ((row & 7) << 4)));
    ushort8 rv = *(const ushort8*)(Rbase + (size_t)row * D4 + c8 * 8);
    ushort8 o;
#pragma unroll
    for (int j = 0; j < 8; ++j) o[j] = f2bf(bf2f(lv[j]) + bf2f(rv[j]));
    *(ushort8*)(Fbase + (size_t)row * 512 + c8 * 8) = o;
  }
}

// ---------------- LayerNorm over 512 bf16 ----------------
template<int HAS_RES, int OUT_F32>
__global__ __launch_bounds__(256)
void ln_bf(const u16* __restrict__ in, const u16* __restrict__ res,
           const float* __restrict__ gamma, const float* __restrict__ beta,
           u16* __restrict__ outb, float* __restrict__ outf)
{
  const int l = threadIdx.x & 63;
  const size_t row = (size_t)blockIdx.x * 4 + (threadIdx.x >> 6);
  ushort8 iv = *(const ushort8*)(in + row * 512 + l * 8);
  float x[8];
#pragma unroll
  for (int j = 0; j < 8; ++j) x[j] = bf2f(iv[j]);
  if (HAS_RES) {
    ushort8 rv = *(const ushort8*)(res + row * 512 + l * 8);
#pragma unroll
    for (int j = 0; j < 8; ++j) x[j] += bf2f(rv[j]);
  }
  float s = 0.f, ss = 0.f;
#pragma unroll
  for (int j = 0; j < 8; ++j) { s += x[j]; ss += x[j] * x[j]; }
#pragma unroll
  for (int m = 1; m < 64; m <<= 1) { s += __shfl_xor(s, m); ss += __shfl_xor(ss, m); }
  float mean = s * (1.f / 512.f);
  float var = fmaxf((ss - 512.f * mean * mean) * (1.f / 511.f), 0.f);
  float inv = 1.f / (sqrtf(var) + 1e-8f);
  const float4* g4 = (const float4*)gamma;
  const float4* b4 = (const float4*)beta;
  float4 g0 = g4[l * 2], g1 = g4[l * 2 + 1];
  float4 b0 = b4[l * 2], b1 = b4[l * 2 + 1];
  float gg[8] = {g0.x, g0.y, g0.z, g0.w, g1.x, g1.y, g1.z, g1.w};
  float bb[8] = {b0.x, b0.y, b0.z, b0.w, b1.x, b1.y, b1.z, b1.w};
  float y[8];
#pragma unroll
  for (int j = 0; j < 8; ++j) y[j] = gg[j] * (x[j] - mean) * inv + bb[j];
  if (outb) {
    ushort8 o;
#pragma unroll
    for (int j = 0; j < 8; ++j) o[j] = f2bf(y[j]);
    *(ushort8*)(outb + row * 512 + l * 8) = o;
  }
  if (OUT_F32) {
    float4* o4 = (float4*)(outf + row * 512);
    o4[l * 2]     = make_float4(y[0], y[1], y[2], y[3]);
    o4[l * 2 + 1] = make_float4(y[4], y[5], y[6], y[7]);
  }
}

extern "C" void kernel_launch(void* const* d_in, const int* in_sizes, int n_in,
                              void* d_out, int out_size, void* d_ws, size_t ws_size,
                              hipStream_t stream)
{
  const int B = 32, S = 512, D = 512, NB = 2, DF = 2048;
  const int M = B * S;

  const float* x   = (const float*)d_in[0];
  const float* ga  = (const float*)d_in[9];
  const float* ba  = (const float*)d_in[10];
  const float* wc1 = (const float*)d_in[11];
  const float* bc1 = (const float*)d_in[12];
  const float* wc2 = (const float*)d_in[13];
  const float* bc2 = (const float*)d_in[14];
  const float* gf  = (const float*)d_in[15];
  const float* bfp = (const float*)d_in[16];

  char* ws = (char*)d_ws;
  u16*   curb = (u16*)(ws + 0);                    // 16 MB
  u16*   qkvr = (u16*)(ws + 16777216);             // 64 MB (aliases Ih)
  u16*   F    = (u16*)(ws + 83886080);             // 16 MB (aliases Y)
  u16*   Hg   = (u16*)(ws + 100663296);            // 16 MB
  u16*   VT   = (u16*)(ws + 117440512);            // 16 MB
  u16*   w4b  = (u16*)(ws + 134217728);            // 4 MB
  u16*   wc1b = (u16*)(ws + 138412032);            // 4 MB
  u16*   wc2b = (u16*)(ws + 142606336);            // 4 MB
  float* b4   = (float*)(ws + 146800640);          // 16 KB
  u16*   Ih   = qkvr;
  u16*   Y    = F;

  castk<<<M * D / 2048, 256, 0, stream>>>(x, curb, M * D, 1.0f);
  castw4<<<1024, 256, 0, stream>>>((const float*)d_in[1], (const float*)d_in[3],
                                   (const float*)d_in[5], (const float*)d_in[7], w4b);
  biasg<<<16, 256, 0, stream>>>((const float*)d_in[2], (const float*)d_in[4],
                                (const float*)d_in[6], (const float*)d_in[8], b4);
  castk<<<NB * DF * D / 2048, 256, 0, stream>>>(wc1, wc1b, NB * DF * D, 1.0f);
  castk<<<NB * DF * D / 2048, 256, 0, stream>>>(wc2, wc2b, NB * DF * D, 1.0f);

  for (int i = 0; i < NB; ++i) {
    const size_t wfo = (size_t)i * DF * D;
    gemm97<1, 1><<<128 * 16, 256, 0, stream>>>(curb, w4b + (size_t)i * 1048576,
                                               b4 + i * 2048, qkvr, VT, M, 2048, 512);
    attn_kernel<<<4 * 256, 256, 0, stream>>>(qkvr, VT, F);
    ln_bf<0, 0><<<M / 4, 256, 0, stream>>>(F, nullptr, ga + i * D, ba + i * D, Hg, nullptr);
    gemm97<1, 0><<<128 * 16, 256, 0, stream>>>(Hg, wc1b + wfo, bc1 + i * DF,
                                               Ih, nullptr, M, 2048, 512);
    gemm97<0, 0><<<128 * 4, 256, 0, stream>>>(Ih, wc2b + wfo, bc2 + i * D,
                                              Y, nullptr, M, 512, 2048);
    if (i == NB - 1)
      ln_bf<1, 1><<<M / 4, 256, 0, stream>>>(Y, Hg, gf + i * D, bfp + i * D,
                                             nullptr, (float*)d_out);
    else
      ln_bf<1, 0><<<M / 4, 256, 0, stream>>>(Y, Hg, gf + i * D, bfp + i * D,
                                             curb, nullptr);
  }
}